// Round 4
// baseline (306.603 us; speedup 1.0000x reference)
//
#include <hip/hip_runtime.h>
#include <hip/hip_bf16.h>
#include <stdint.h>
#include <stddef.h>

// ---------------- problem constants ----------------
#define B_ 4
#define T_ 2048
#define C_ 1024
#define H_ 16
#define D_ 64
#define M_ (B_ * T_)   // 8192 rows of x

typedef __bf16 bf16x8 __attribute__((ext_vector_type(8)));
typedef float  f32x4  __attribute__((ext_vector_type(4)));
typedef unsigned short u16x8 __attribute__((ext_vector_type(8)));
typedef unsigned short u16x4 __attribute__((ext_vector_type(4)));
typedef unsigned int   u32x4 __attribute__((ext_vector_type(4)));

__device__ __forceinline__ unsigned short f2bf(float f) {
    union { float f; unsigned int u; } c; c.f = f;
    unsigned int u = c.u;
    unsigned int r = (u + 0x7fffu + ((u >> 16) & 1u)) >> 16;
    return (unsigned short)r;
}

// pack two f32 -> one dword of 2 bf16 (round-half-up; <=1ulp vs RNE).
__device__ __forceinline__ unsigned int pack2bf(float a, float b) {
    unsigned int ua = __builtin_bit_cast(unsigned int, a) + 0x8000u;
    unsigned int ub = __builtin_bit_cast(unsigned int, b) + 0x8000u;
    return __builtin_amdgcn_perm(ub, ua, 0x07060302u);
}

__device__ __forceinline__ bf16x8 ld_bf16x8(const unsigned short* p) {
    u16x8 v = *(const u16x8*)p;
    return __builtin_bit_cast(bf16x8, v);
}

// async global -> LDS, 16 B per lane (dest = uniform base + lane*16)
__device__ __forceinline__ void gl_lds16(const unsigned short* g, unsigned short* l) {
    __builtin_amdgcn_global_load_lds(
        (const void __attribute__((address_space(1)))*)g,
        (void __attribute__((address_space(3)))*)l, 16, 0, 0);
}

__device__ __forceinline__ f32x4 vmax4(f32x4 a, f32x4 b) {
    f32x4 r;
    r.x = fmaxf(a.x, b.x); r.y = fmaxf(a.y, b.y);
    r.z = fmaxf(a.z, b.z); r.w = fmaxf(a.w, b.w);
    return r;
}

// ============================================================
// Kernel 0: fp32 -> bf16 conversion of x and {Wq,Wk,Wv} (concat).
// ============================================================
#define X4_ ((int64_t)M_ * C_ / 4)   // 2,097,152 float4s
#define W4_ ((int64_t)C_ * C_ / 4)   //   262,144 float4s per W

__global__ __launch_bounds__(256)
void cvt_bf16(const float* __restrict__ x,
              const float* __restrict__ Wq, const float* __restrict__ Wk,
              const float* __restrict__ Wv,
              unsigned short* __restrict__ xb, unsigned short* __restrict__ wb)
{
    const int64_t i4 = (int64_t)blockIdx.x * blockDim.x + threadIdx.x;
    const float* src; unsigned short* dst; int64_t off;
    if (i4 < X4_) { src = x; dst = xb; off = i4; }
    else {
        int64_t j = i4 - X4_;
        int which = (int)(j / W4_);
        off = j - (int64_t)which * W4_;
        src = (which == 0) ? Wq : (which == 1) ? Wk : Wv;
        dst = wb + (int64_t)which * C_ * C_;
    }
    f32x4 v = *(const f32x4*)(src + off * 4);
    u16x4 o = { f2bf(v.x), f2bf(v.y), f2bf(v.z), f2bf(v.w) };
    *(u16x4*)(dst + off * 4) = o;
}

// ============================================================
// Kernel 1: y = xb @ Wb^T + b, N concat = 3072. Pure bf16 MFMA.
// XCD-chunked block swizzle (bijective: 1536 = 8*192): each XCD owns
// 8 contiguous bm-groups x all 24 bn -> the x-panel stays L2-hot.
// Outputs identical to the verified round-0 kernel (q pre-scaled bf16,
// k bf16, v bf16 in permuted [B,H,D,T]).
// ============================================================
#define K1_ 0.180336880f   // 0.125 * log2(e)

__global__ __launch_bounds__(256)
void qkv_gemm(const unsigned short* __restrict__ xb,
              const unsigned short* __restrict__ wb,
              const float* __restrict__ bq, const float* __restrict__ bk,
              const float* __restrict__ bv,
              unsigned short* __restrict__ qo,
              unsigned short* __restrict__ ko,
              unsigned short* __restrict__ vo)
{
    __shared__ alignas(16) unsigned short As[128 * 64];
    __shared__ alignas(16) unsigned short Bs[128 * 64];

    const int tid  = threadIdx.x;
    const int flat = blockIdx.x;
    const int t    = (flat & 7) * 192 + (flat >> 3);   // bijective XCD chunks
    const int bm   = t / 24;               // 0..63
    const int bnF  = t - bm * 24;          // 0..23
    const int which = bnF >> 3;            // 0=q 1=k 2=v
    const int n_base = (bnF & 7) * 128;
    const int nrow   = bnF * 128;
    const int m_base = bm * 128;

    const float* bias = (which == 0) ? bq : (which == 1) ? bk : bv;

    const int w = tid >> 6, lane = tid & 63;
    const int wr = w >> 1, wc = w & 1;
    const int ln = lane & 15, quad = lane >> 4;

    const int srow   = lane >> 3;                  // 0..7
    const int schunk = (lane & 7) ^ srow;          // 0..7
    const int scu    = schunk * 8;

    const f32x4 fz = {0.f, 0.f, 0.f, 0.f};
    f32x4 acc[4][4];
#pragma unroll
    for (int i = 0; i < 4; ++i)
#pragma unroll
        for (int j = 0; j < 4; ++j) acc[i][j] = fz;

    for (int k0 = 0; k0 < C_; k0 += 64) {
        __syncthreads();
#pragma unroll
        for (int i = 0; i < 4; ++i) {
            const int r = w * 32 + i * 8 + srow;
            gl_lds16(xb + (size_t)(m_base + r) * C_ + k0 + scu, As + (w * 4 + i) * 512);
            gl_lds16(wb + (size_t)(nrow  + r) * C_ + k0 + scu, Bs + (w * 4 + i) * 512);
        }
        __syncthreads();

#pragma unroll
        for (int kk = 0; kk < 2; ++kk) {
            bf16x8 af[4], bfr[4];
#pragma unroll
            for (int mi = 0; mi < 4; ++mi) {
                const int r = wr * 64 + mi * 16 + ln;
                af[mi] = ld_bf16x8(&As[r * 64 + (((kk * 4 + quad) ^ (ln & 7)) * 8)]);
            }
#pragma unroll
            for (int ni = 0; ni < 4; ++ni) {
                const int r = wc * 64 + ni * 16 + ln;
                bfr[ni] = ld_bf16x8(&Bs[r * 64 + (((kk * 4 + quad) ^ (ln & 7)) * 8)]);
            }
#pragma unroll
            for (int mi = 0; mi < 4; ++mi)
#pragma unroll
                for (int ni = 0; ni < 4; ++ni)
                    acc[mi][ni] = __builtin_amdgcn_mfma_f32_16x16x32_bf16(
                        af[mi], bfr[ni], acc[mi][ni], 0, 0, 0);
        }
    }

#pragma unroll
    for (int ni = 0; ni < 4; ++ni) {
        const int n_local = n_base + wc * 64 + ni * 16 + ln;   // 0..1023
        const float bv_ = bias[n_local];
        const int h = n_local >> 6, d = n_local & 63;
#pragma unroll
        for (int mi = 0; mi < 4; ++mi) {
            const int m0 = m_base + wr * 64 + mi * 16 + quad * 4;
            const int b  = m0 >> 11;
            const int t0 = m0 & (T_ - 1);
            f32x4 v = acc[mi][ni];
            if (which == 2) {
                // permuted [B,H,D,T]: within each 128-kv block,
                // pos(kv) = (kvt>>1)*32 + qd*8 + (kvt&1)*4 + j, kvt=kv>>4
                const int tb   = t0 & ~127;
                const int w128 = t0 & 127;
                const int kvt  = w128 >> 4;
                const int qd   = (w128 >> 2) & 3;
                const int pos  = (kvt >> 1) * 32 + qd * 8 + (kvt & 1) * 4;
                u16x4 pk = { f2bf(v.x + bv_), f2bf(v.y + bv_),
                             f2bf(v.z + bv_), f2bf(v.w + bv_) };
                *(u16x4*)(&vo[((size_t)(b * H_ + h) * D_ + d) * T_ + tb + pos]) = pk;
            } else if (which == 0) {
                unsigned short* dst =
                    qo + ((size_t)(b * H_ + h) * T_ + t0) * (size_t)D_ + d;
                dst[0 * D_] = f2bf((v.x + bv_) * K1_);
                dst[1 * D_] = f2bf((v.y + bv_) * K1_);
                dst[2 * D_] = f2bf((v.z + bv_) * K1_);
                dst[3 * D_] = f2bf((v.w + bv_) * K1_);
            } else {
                unsigned short* dst =
                    ko + ((size_t)(b * H_ + h) * T_ + t0) * (size_t)D_ + d;
                dst[0 * D_] = f2bf(v.x + bv_);
                dst[1 * D_] = f2bf(v.y + bv_);
                dst[2 * D_] = f2bf(v.z + bv_);
                dst[3 * D_] = f2bf(v.w + bv_);
            }
        }
    }
}

// ============================================================
// Kernel 2: flash attention, S^T form. 4 waves x 64 q rows each
// (4 subtiles/wave) = 256 q rows/block. Each wave's full K+V LDS read
// (32 x ds_read_b128/iter, the measured bottleneck) now covers 2x the
// q rows of the round-0 kernel -> LDS cycles per unit work halve.
//
// Numerics = EXACTLY round-0's verified components, refactored so no
// s[8] live range is needed (4 subtiles fit in registers):
//   e = exp2(s - m2_old) computed inline in the QK loop (bf16 pack2bf,
//   proven); PV (bf16 mfma, proven V layout) runs at the OLD scale;
//   monotone max update happens AFTER PV: when any row improves by >8,
//   fl = exp2(m2_old - m2_new) multiplies acc and (li+rs). Algebraically
//   identical to round-0's online softmax; bf16/f32 absorb the <=2^8
//   transient range with huge headroom.
// Row-sum via per-lane f32 adds + shfl reduce (proven round-0 pattern).
// ============================================================
__global__ __launch_bounds__(256, 2)
void flash_attn(const unsigned short* __restrict__ qb,
                const unsigned short* __restrict__ kb,
                const unsigned short* __restrict__ vtb,
                float* __restrict__ out)
{
    __shared__ alignas(16) unsigned char smem[49152];   // K dbuf 2x16K | V 16K
    float* Os = (float*)smem;                           // [128][72] epilogue overlay
    unsigned short* Vs = (unsigned short*)(smem + 32768);

    const int tid = threadIdx.x;
    // XCD swizzle: 512 blocks, 64 contiguous logical tiles per XCD.
    const int flat = blockIdx.x;                 // 0..511
    const int tile = (flat & 7) * 64 + (flat >> 3);
    const int qt   = tile & 7;                   // 0..7 (256 q rows each)
    const int bh   = tile >> 3;                  // 0..63
    const int b    = bh >> 4, h = bh & 15;

    const int w = tid >> 6, lane = tid & 63;
    const int ln = lane & 15, quad = lane >> 4;

    const unsigned short* Qb = qb  + (size_t)bh * T_ * D_;
    const unsigned short* Kb = kb  + (size_t)bh * T_ * D_;
    const unsigned short* Vb = vtb + (size_t)bh * D_ * T_;

    // Q (pre-scaled) as B-operand fragments, 4 subtiles of 16 rows
    bf16x8 qf[4][2];
#pragma unroll
    for (int X = 0; X < 4; ++X) {
        const int qr = qt * 256 + X * 64 + w * 16 + ln;
        qf[X][0] = ld_bf16x8(&Qb[(size_t)qr * D_ + quad * 8]);
        qf[X][1] = ld_bf16x8(&Qb[(size_t)qr * D_ + 32 + quad * 8]);
    }

    // K staging: instr i -> 8 rows of 128B, swizzled chunks
    const int srow   = lane >> 3;
    const int schunk = (lane & 7) ^ srow;
    const int scu    = schunk * 8;
    // V staging: instr i -> 4 rows of 256B; source chunk swizzled
    const int vrow = lane >> 4;          // 0..3

    const f32x4 fz = {0.f, 0.f, 0.f, 0.f};
    f32x4 acc[4][4];                     // [subtile][dt] : O^T[d][q]
    float m2[4] = {0.f, 0.f, 0.f, 0.f};  // running max, log2 domain, monotone
    float li[4] = {0.f, 0.f, 0.f, 0.f};  // row sums at scale 2^-m2
#pragma unroll
    for (int X = 0; X < 4; ++X)
#pragma unroll
        for (int dt = 0; dt < 4; ++dt) acc[X][dt] = fz;

    auto stageK = [&](int kv0_, int buf) {
        unsigned short* Ksw = (unsigned short*)(smem + buf * 16384);
#pragma unroll
        for (int i = 0; i < 4; ++i) {
            const int kr = kv0_ + w * 32 + i * 8 + srow;
            gl_lds16(Kb + (size_t)kr * D_ + scu, Ksw + (w * 4 + i) * 512);
        }
    };
    auto stageV = [&](int kv0_) {
#pragma unroll
        for (int i = 0; i < 4; ++i) {
            const int dr = (w * 4 + i) * 4 + vrow;
            const int vcs = (lane & 15) ^ ((i & 1) * 4 + vrow);   // src chunk
            gl_lds16(Vb + (size_t)dr * T_ + kv0_ + vcs * 8, Vs + (w * 4 + i) * 512);
        }
    };

    stageK(0, 0);   // preload K tile 0

    for (int kv0 = 0; kv0 < T_; kv0 += 128) {
        const int cur = (kv0 >> 7) & 1;
        // barrier A: drains K(cur) prefetch; all waves done with prev V reads
        __syncthreads();
        stageV(kv0);                                      // V for THIS iter
        if (kv0 + 128 < T_) stageK(kv0 + 128, cur ^ 1);   // K for NEXT iter

        const unsigned short* Ks = (const unsigned short*)(smem + cur * 16384);

        // S^T = K . Q^T, 4 subtiles sharing K fragments; exp2 with the
        // (stale, monotone) running max computed inline; bf16 pack.
        u32x4 pks[4][4];     // [subtile][p]
        f32x4 mm[4], rsv[4];
#pragma unroll
        for (int X = 0; X < 4; ++X) {
            mm[X]  = {-3.0e38f, -3.0e38f, -3.0e38f, -3.0e38f};
            rsv[X] = fz;
        }

#pragma unroll
        for (int kvt = 0; kvt < 8; ++kvt) {
            const int r_ = kvt * 16 + ln;               // r_&7 == ln&7
            bf16x8 kf0 = ld_bf16x8(&Ks[r_ * 64 + ((quad)     ^ (ln & 7)) * 8]);
            bf16x8 kf1 = ld_bf16x8(&Ks[r_ * 64 + ((quad + 4) ^ (ln & 7)) * 8]);
#pragma unroll
            for (int X = 0; X < 4; ++X) {
                f32x4 s = fz;
                s = __builtin_amdgcn_mfma_f32_16x16x32_bf16(kf0, qf[X][0], s, 0, 0, 0);
                s = __builtin_amdgcn_mfma_f32_16x16x32_bf16(kf1, qf[X][1], s, 0, 0, 0);
                mm[X] = vmax4(mm[X], s);
                f32x4 e;
                e.x = __builtin_amdgcn_exp2f(s.x - m2[X]);
                e.y = __builtin_amdgcn_exp2f(s.y - m2[X]);
                e.z = __builtin_amdgcn_exp2f(s.z - m2[X]);
                e.w = __builtin_amdgcn_exp2f(s.w - m2[X]);
                rsv[X] += e;
                pks[X][kvt >> 1][(kvt & 1) * 2]     = pack2bf(e.x, e.y);
                pks[X][kvt >> 1][(kvt & 1) * 2 + 1] = pack2bf(e.z, e.w);
            }
        }

        // per-row reductions; decide rescale factor (applied AFTER PV so
        // pks never needs touching). li update is exact at either scale.
        float fl[4];
#pragma unroll
        for (int X = 0; X < 4; ++X) {
            float mx = fmaxf(fmaxf(mm[X].x, mm[X].y), fmaxf(mm[X].z, mm[X].w));
            mx = fmaxf(mx, __shfl_xor(mx, 16));
            mx = fmaxf(mx, __shfl_xor(mx, 32));
            float rs = (rsv[X].x + rsv[X].y) + (rsv[X].z + rsv[X].w);
            rs += __shfl_xor(rs, 16);
            rs += __shfl_xor(rs, 32);
            if (__any(mx > m2[X] + 8.0f)) {
                const float nm = fmaxf(m2[X], mx);      // monotone
                fl[X] = __builtin_amdgcn_exp2f(m2[X] - nm);
                li[X] = (li[X] + rs) * fl[X];
                m2[X] = nm;
            } else {
                fl[X] = 1.0f;
                li[X] += rs;
            }
        }

        // barrier B: drains V(cur) staging (K(next) prefetch also drains,
        // but it had the whole S^T+softmax phase to land)
        __syncthreads();

        // O^T += V^T . P^T via bf16 16x16x32; each vv feeds 4 subtiles
#pragma unroll
        for (int dt = 0; dt < 4; ++dt) {
            const int vr = dt * 16 + ln;
#pragma unroll
            for (int p = 0; p < 4; ++p) {
                const int cl = ((p * 4 + quad) ^ (ln & 7));
                bf16x8 vv = ld_bf16x8(&Vs[vr * 128 + cl * 8]);
#pragma unroll
                for (int X = 0; X < 4; ++X)
                    acc[X][dt] = __builtin_amdgcn_mfma_f32_16x16x32_bf16(
                        vv, __builtin_bit_cast(bf16x8, pks[X][p]), acc[X][dt], 0, 0, 0);
            }
        }

        // bring acc (including this tile's PV, added at the old scale)
        // to the new scale; fl==1.0 on non-improving tiles.
#pragma unroll
        for (int X = 0; X < 4; ++X)
#pragma unroll
            for (int dt = 0; dt < 4; ++dt) acc[X][dt] *= fl[X];
    }

    // epilogue: normalize, transpose O^T -> O via LDS, two 128-row passes
    float rv[4];
#pragma unroll
    for (int X = 0; X < 4; ++X) rv[X] = 1.0f / li[X];

    const int q  = tid >> 1;              // 0..127
    const int c0 = (tid & 1) * 32;
    __syncthreads();
#pragma unroll
    for (int g = 0; g < 2; ++g) {
#pragma unroll
        for (int xi = 0; xi < 2; ++xi) {
            const int X = g * 2 + xi;
#pragma unroll
            for (int dt = 0; dt < 4; ++dt)
#pragma unroll
                for (int r = 0; r < 4; ++r)
                    Os[(xi * 64 + w * 16 + ln) * 72 + dt * 16 + quad * 4 + r] =
                        acc[X][dt][r] * rv[X];
        }
        __syncthreads();
        const float* src = &Os[q * 72 + c0];
        float* dst = &out[((size_t)(b * T_ + qt * 256 + g * 128 + q)) * C_ + h * 64 + c0];
#pragma unroll
        for (int i = 0; i < 8; ++i)
            *(f32x4*)(dst + i * 4) = *(const f32x4*)(src + i * 4);
        __syncthreads();
    }
}

// ============================================================
extern "C" void kernel_launch(void* const* d_in, const int* in_sizes, int n_in,
                              void* d_out, int out_size, void* d_ws, size_t ws_size,
                              hipStream_t stream) {
    const float* q_x = (const float*)d_in[0];
    const float* Wq  = (const float*)d_in[1];
    const float* bq  = (const float*)d_in[2];
    const float* Wk  = (const float*)d_in[3];
    const float* bk  = (const float*)d_in[4];
    const float* Wv  = (const float*)d_in[5];
    const float* bv  = (const float*)d_in[6];
    float* out = (float*)d_out;

    const size_t elems = (size_t)M_ * C_;      // 8,388,608
    unsigned short* xb  = (unsigned short*)d_ws;
    unsigned short* wb  = xb + elems;                    // 3*C*C
    unsigned short* qb  = wb + (size_t)3 * C_ * C_;
    unsigned short* kb  = qb + elems;
    unsigned short* vtb = kb + elems;
    (void)ws_size; (void)in_sizes; (void)n_in; (void)out_size;

    const int64_t total4 = X4_ + 3 * W4_;      // 2,883,584
    cvt_bf16<<<(int)(total4 / 256), 256, 0, stream>>>(q_x, Wq, Wk, Wv, xb, wb);

    qkv_gemm<<<1536, 256, 0, stream>>>(
        xb, wb, bq, bk, bv, qb, kb, vtb);

    flash_attn<<<512, 256, 0, stream>>>(qb, kb, vtb, out);
}